// Round 14
// baseline (348.012 us; speedup 1.0000x reference)
//
#include <hip/hip_runtime.h>
#include <hip/hip_bf16.h>

#define D 128
#define LDK 136  // padded LDS row: 136 bf16 = 272B

typedef __bf16 bf16x8 __attribute__((ext_vector_type(8)));
typedef float  f32x4  __attribute__((ext_vector_type(4)));
typedef unsigned int u32x4 __attribute__((ext_vector_type(4)));
typedef unsigned short u16;
typedef unsigned long long u64;

__device__ __forceinline__ u16 f2bf(float f) {
    unsigned int u = __builtin_bit_cast(unsigned int, f);
    u = u + 0x7FFFu + ((u >> 16) & 1u);
    return (u16)(u >> 16);
}
__device__ __forceinline__ float bf2f(u16 h) {
    unsigned int u = ((unsigned int)h) << 16;
    return __builtin_bit_cast(float, u);
}
__device__ __forceinline__ unsigned int pk2(float lo, float hi) {
    return (unsigned int)f2bf(lo) | ((unsigned int)f2bf(hi) << 16);
}
__device__ __forceinline__ void cvt_store8(u16* dst, float4 a, float4 b) {
    uint4 v;
    v.x = pk2(a.x, a.y); v.y = pk2(a.z, a.w);
    v.z = pk2(b.x, b.y); v.w = pk2(b.z, b.w);
    *reinterpret_cast<uint4*>(dst) = v;
}
__device__ __forceinline__ bf16x8 cvt8r(f32x4 a, f32x4 b) {
    u32x4 v;
    v.x = pk2(a.x, a.y); v.y = pk2(a.z, a.w);
    v.z = pk2(b.x, b.y); v.w = pk2(b.z, b.w);
    return __builtin_bit_cast(bf16x8, v);
}

// ======== fused pre-pass: x->bf16 convert (blocks [0,xblocks)) + dst hist ========
__global__ __launch_bounds__(256)
void pre_kernel(const float* __restrict__ x, u16* __restrict__ xbf, int total8,
                const int* __restrict__ ei, int* __restrict__ counts, int E,
                int xblocks) {
    const int b = blockIdx.x;
    if (b < xblocks) {
        int i = b * 256 + threadIdx.x;
        if (i < total8) {
            const f32x4* g = reinterpret_cast<const f32x4*>(x + (size_t)i * 8);
            f32x4 a = g[0], c = g[1];
            u32x4 v;
            v.x = pk2(a.x, a.y); v.y = pk2(a.z, a.w);
            v.z = pk2(c.x, c.y); v.w = pk2(c.z, c.w);
            *reinterpret_cast<u32x4*>(xbf + (size_t)i * 8) = v;
        }
    } else {
        int e = (b - xblocks) * 256 + threadIdx.x;
        if (e < E) atomicAdd(&counts[ei[E + e]], 1);
    }
}

// ======== 3-pass scan ========
__global__ __launch_bounds__(256)
void scan_partial(const int* __restrict__ counts, int* __restrict__ bsum) {
    const int b = blockIdx.x, t = threadIdx.x;
    const int4 v = reinterpret_cast<const int4*>(counts + (size_t)b * 1024)[t];
    int s = v.x + v.y + v.z + v.w;
    #pragma unroll
    for (int off = 1; off < 64; off <<= 1) s += __shfl_xor(s, off);
    __shared__ int ws[4];
    if ((t & 63) == 0) ws[t >> 6] = s;
    __syncthreads();
    if (t == 0) bsum[b] = ws[0] + ws[1] + ws[2] + ws[3];
}
__global__ __launch_bounds__(256)
void scan_bsum(int* __restrict__ bsum, int nb) {
    const int t = threadIdx.x;
    int s = (t < nb) ? bsum[t] : 0;
    int inc = s;
    const int lane = t & 63;
    #pragma unroll
    for (int off = 1; off < 64; off <<= 1) {
        int v = __shfl_up(inc, off);
        if (lane >= off) inc += v;
    }
    __shared__ int ws[4];
    if (lane == 63) ws[t >> 6] = inc;
    __syncthreads();
    int woff = 0;
    for (int i = 0; i < (t >> 6); ++i) woff += ws[i];
    if (t < nb) bsum[t] = woff + inc - s;
}
__global__ __launch_bounds__(256)
void scan_emit(const int* __restrict__ counts, const int* __restrict__ bsum,
               int* __restrict__ offsets) {
    const int b = blockIdx.x, t = threadIdx.x;
    const int4 v = reinterpret_cast<const int4*>(counts + (size_t)b * 1024)[t];
    const int s = v.x + v.y + v.z + v.w;
    int inc = s;
    const int lane = t & 63;
    #pragma unroll
    for (int off = 1; off < 64; off <<= 1) {
        int u = __shfl_up(inc, off);
        if (lane >= off) inc += u;
    }
    __shared__ int ws[4];
    if (lane == 63) ws[t >> 6] = inc;
    __syncthreads();
    int woff = bsum[b];
    for (int i = 0; i < (t >> 6); ++i) woff += ws[i];
    int e0 = woff + inc - s;
    int4 o;
    o.x = e0; o.y = e0 + v.x; o.z = o.y + v.y; o.w = o.z + v.z;
    reinterpret_cast<int4*>(offsets + (size_t)b * 1024)[t] = o;
}

// scatter: packed 8B record (eid 20b | src 17b | dst 17b); 6.4MB buffer -> L2-resident
__global__ __launch_bounds__(256)
void scatter_kernel(const int* __restrict__ ei, int* __restrict__ off,
                    u64* __restrict__ rec, int E) {
    int e = blockIdx.x * 256 + threadIdx.x;
    if (e < E) {
        u64 s = (u64)ei[e];
        u64 d = (u64)ei[E + e];
        int p = atomicAdd(&off[(int)d], 1);
        rec[p] = (u64)e | (s << 20) | (d << 37);
    }
}

// ======== persistent edge kernel with CROSS-TILE PREFETCH ========
// Double-buffered rec in LDS; tile t+1's ea+x loads issued after tile t's B2 so
// they fly across the reduce. B3 is a raw s_barrier + lgkmcnt(0) only (no vmcnt
// drain) so prefetch survives the barrier.
__global__ __launch_bounds__(256, 2)
void gine_edge_pers(const u16* __restrict__ xbf,
                    const float* __restrict__ ea,
                    const float* __restrict__ We,
                    const float* __restrict__ be,
                    const u64* __restrict__ rec,
                    float* __restrict__ aggr,
                    int E, int ntiles)
{
    __shared__ u16 wbuf[128][LDK];   // We bf16, resident
    __shared__ u16 mbuf[128][LDK];   // x -> msg per tile
    __shared__ int eid_lds[2][128];
    __shared__ int src_lds[2][128];
    __shared__ int dst_lds[2][128];

    const int tid = threadIdx.x;
    const int wave = tid >> 6, lane = tid & 63;
    const int lhi = lane >> 4, llo = lane & 15;
    const int r0 = wave * 32;
    const int xrow = tid >> 1;
    const int xc0  = (tid & 1) * 64;

    {   // stage We once
        const int row = tid >> 1;
        const int c0  = (tid & 1) * 64;
        const float4* gw = reinterpret_cast<const float4*>(We + (size_t)row * D + c0);
        #pragma unroll
        for (int j = 0; j < 8; ++j) {
            float4 w0 = gw[2*j], w1 = gw[2*j+1];
            cvt_store8(&wbuf[row][c0 + 8*j], w0, w1);
        }
    }
    float bev[8];
    #pragma unroll
    for (int nf = 0; nf < 8; ++nf) bev[nf] = be[nf*16 + llo];

    // stage rec for first tile into buf 0
    if (tid < 128) {
        const int p = blockIdx.x * 128 + tid;
        if (p < E) {
            u64 v = rec[p];
            eid_lds[0][tid] = (int)(v & 0xFFFFFu);
            src_lds[0][tid] = (int)((v >> 20) & 0x1FFFFu);
            dst_lds[0][tid] = (int)(v >> 37);
        } else {
            eid_lds[0][tid] = 0; src_lds[0][tid] = 0; dst_lds[0][tid] = -1;
        }
    }
    __syncthreads();

    f32x4 ga[16];   // full A tile per lane: [kk*4 + {pa0,pa1,pb0,pb1}]
    u32x4 xa[8];    // x row (bf16, 128B)

#define ISSUE(BUF) {                                                            \
        const f32x4* pa_ = reinterpret_cast<const f32x4*>(                      \
            ea + (size_t)eid_lds[BUF][r0 + llo] * D);                           \
        const f32x4* pb_ = reinterpret_cast<const f32x4*>(                      \
            ea + (size_t)eid_lds[BUF][r0 + 16 + llo] * D);                      \
        const u32x4* gx_ = reinterpret_cast<const u32x4*>(                      \
            xbf + (size_t)src_lds[BUF][xrow] * D + xc0);                        \
        _Pragma("unroll")                                                       \
        for (int kk = 0; kk < 4; ++kk) {                                        \
            const int f4_ = (kk*32 + lhi*8) >> 2;                               \
            ga[kk*4+0] = __builtin_nontemporal_load(pa_ + f4_);                 \
            ga[kk*4+1] = __builtin_nontemporal_load(pa_ + f4_ + 1);             \
            ga[kk*4+2] = __builtin_nontemporal_load(pb_ + f4_);                 \
            ga[kk*4+3] = __builtin_nontemporal_load(pb_ + f4_ + 1);             \
        }                                                                       \
        _Pragma("unroll")                                                       \
        for (int j = 0; j < 8; ++j) xa[j] = gx_[j]; }

    ISSUE(0);
    int cur = 0;

    for (int tile = blockIdx.x; tile < ntiles; tile += gridDim.x) {
        const int e0  = tile * 128;
        const int nxt = tile + gridDim.x;

        // stage next tile's rec into cur^1 (read after B2)
        if (tid < 128 && nxt < ntiles) {
            const int p = nxt * 128 + tid;
            if (p < E) {
                u64 v = rec[p];
                eid_lds[cur^1][tid] = (int)(v & 0xFFFFFu);
                src_lds[cur^1][tid] = (int)((v >> 20) & 0x1FFFFu);
                dst_lds[cur^1][tid] = (int)(v >> 37);
            } else {
                eid_lds[cur^1][tid] = 0; src_lds[cur^1][tid] = 0;
                dst_lds[cur^1][tid] = -1;
            }
        }

        // MFMA consuming in-flight ga
        f32x4 acc[2][8];
        #pragma unroll
        for (int m = 0; m < 2; ++m)
            #pragma unroll
            for (int n = 0; n < 8; ++n) acc[m][n] = (f32x4){0.f, 0.f, 0.f, 0.f};
        #pragma unroll
        for (int kk = 0; kk < 4; ++kk) {
            bf16x8 a0 = cvt8r(ga[kk*4+0], ga[kk*4+1]);
            bf16x8 a1 = cvt8r(ga[kk*4+2], ga[kk*4+3]);
            const int k0 = kk*32 + lhi*8;
            #pragma unroll
            for (int nf = 0; nf < 8; ++nf) {
                bf16x8 b = *reinterpret_cast<const bf16x8*>(&wbuf[nf*16 + llo][k0]);
                acc[0][nf] = __builtin_amdgcn_mfma_f32_16x16x32_bf16(a0, b, acc[0][nf], 0, 0, 0);
                acc[1][nf] = __builtin_amdgcn_mfma_f32_16x16x32_bf16(a1, b, acc[1][nf], 0, 0, 0);
            }
        }

        // x -> mbuf (wave-local rows), then in-place epilogue
        #pragma unroll
        for (int j = 0; j < 8; ++j)
            *reinterpret_cast<u32x4*>(&mbuf[xrow][xc0 + 8*j]) = xa[j];

        #pragma unroll
        for (int mf = 0; mf < 2; ++mf) {
            #pragma unroll
            for (int r = 0; r < 4; ++r) {
                const int row = r0 + mf*16 + lhi*4 + r;
                const bool valid = (e0 + row) < E;
                #pragma unroll
                for (int nf = 0; nf < 8; ++nf) {
                    const int col = nf*16 + llo;
                    const float v = acc[mf][nf][r] + bf2f(mbuf[row][col]) + bev[nf];
                    mbuf[row][col] = valid ? f2bf(fmaxf(v, 0.0f)) : (u16)0;
                }
            }
        }
        __syncthreads();   // B2: msg + next-rec visible (no prefetch in flight here)

        // PREFETCH next tile's ea + x (flies across reduce and B3)
        if (nxt < ntiles) ISSUE(cur^1);

        // segmented reduce (2 halves; interior run exclusive store, boundary atomic)
        {
            const int c   = tid & 127;
            const int h   = tid >> 7;
            const int rlo = h * 64;
            float sum = 0.0f;
            int prev  = dst_lds[cur][rlo];
            int start = rlo;
            #pragma unroll 4
            for (int r = rlo; r < rlo + 64; ++r) {
                const float v = bf2f(mbuf[r][c]);
                const int d = dst_lds[cur][r];
                if (d != prev) {
                    if (prev >= 0) {
                        float* p = &aggr[(size_t)prev * D + c];
                        if (start == rlo) atomicAdd(p, sum);
                        else              *p = sum;
                    }
                    sum = 0.0f; prev = d; start = r;
                }
                sum += v;
            }
            if (prev >= 0) atomicAdd(&aggr[(size_t)prev * D + c], sum);
        }

        // B3: raw barrier, LDS-drain only — prefetch loads stay in flight
        asm volatile("s_waitcnt lgkmcnt(0)" ::: "memory");
        __builtin_amdgcn_s_barrier();
        asm volatile("" ::: "memory");
        cur ^= 1;
    }
#undef ISSUE
}

// ======== last-resort unsorted edge kernel (ws too small) ========
__global__ __launch_bounds__(256, 4)
void gine_edge(const float* __restrict__ x,
               const int* __restrict__ ei,
               const float* __restrict__ ea,
               const float* __restrict__ We,
               const float* __restrict__ be,
               float* __restrict__ aggr,
               int E)
{
    __shared__ u16 w_lds[128][LDK];
    __shared__ int sd_lds[2][128];

    const int tid = threadIdx.x;
    const int e0  = blockIdx.x * 128;

    {
        const int row = tid >> 1;
        const int c0  = (tid & 1) * 64;
        const float4* gw = reinterpret_cast<const float4*>(We + (size_t)row * D + c0);
        #pragma unroll
        for (int j = 0; j < 8; ++j) {
            float4 w0 = gw[2*j], w1 = gw[2*j+1];
            cvt_store8(&w_lds[row][c0 + 8*j], w0, w1);
        }
        const int r = tid & 127, which = tid >> 7;
        int erow = e0 + r;
        sd_lds[which][r] = (erow < E) ? ei[(size_t)which * E + erow] : 0;
    }
    __syncthreads();

    const int wave = tid >> 6, lane = tid & 63;
    const int lhi = lane >> 4, llo = lane & 15;
    const int r0 = wave * 32;

    f32x4 acc[2][8];
    #pragma unroll
    for (int m = 0; m < 2; ++m)
        #pragma unroll
        for (int n = 0; n < 8; ++n) acc[m][n] = (f32x4){0.f, 0.f, 0.f, 0.f};

    int ra = e0 + r0 + llo;      if (ra >= E) ra = E - 1;
    int rb = e0 + r0 + 16 + llo; if (rb >= E) rb = E - 1;
    const f32x4* pa = reinterpret_cast<const f32x4*>(ea + (size_t)ra * D);
    const f32x4* pb = reinterpret_cast<const f32x4*>(ea + (size_t)rb * D);

    #pragma unroll
    for (int kk = 0; kk < 4; ++kk) {
        const int k0 = kk * 32 + lhi * 8;
        const int f4 = k0 >> 2;
        f32x4 u0 = __builtin_nontemporal_load(pa + f4);
        f32x4 u1 = __builtin_nontemporal_load(pa + f4 + 1);
        f32x4 v0 = __builtin_nontemporal_load(pb + f4);
        f32x4 v1 = __builtin_nontemporal_load(pb + f4 + 1);
        bf16x8 a0 = cvt8r(u0, u1);
        bf16x8 a1 = cvt8r(v0, v1);
        #pragma unroll
        for (int nf = 0; nf < 8; ++nf) {
            bf16x8 b = *reinterpret_cast<const bf16x8*>(&w_lds[nf*16 + llo][k0]);
            acc[0][nf] = __builtin_amdgcn_mfma_f32_16x16x32_bf16(a0, b, acc[0][nf], 0, 0, 0);
            acc[1][nf] = __builtin_amdgcn_mfma_f32_16x16x32_bf16(a1, b, acc[1][nf], 0, 0, 0);
        }
    }

    float bev[8];
    #pragma unroll
    for (int nf = 0; nf < 8; ++nf) bev[nf] = be[nf*16 + llo];

    #pragma unroll
    for (int mf = 0; mf < 2; ++mf) {
        #pragma unroll
        for (int r = 0; r < 4; ++r) {
            const int row = r0 + mf*16 + lhi*4 + r;
            if (e0 + row >= E) continue;
            const int s = sd_lds[0][row];
            const int d = sd_lds[1][row];
            const float* xr  = x    + (size_t)s * D;
            float*      arow = aggr + (size_t)d * D;
            #pragma unroll
            for (int nf = 0; nf < 8; ++nf) {
                const int col = nf*16 + llo;
                float v = acc[mf][nf][r] + xr[col] + bev[nf];
                atomicAdd(&arow[col], fmaxf(v, 0.0f));
            }
        }
    }
}

// ---------------- node kernel ----------------
__global__ __launch_bounds__(256, 2)
void gine_node(const float* __restrict__ x,
               const float* __restrict__ aggr,
               const float* __restrict__ epsp,
               const float* __restrict__ W1,
               const float* __restrict__ b1,
               const float* __restrict__ bn_g,
               const float* __restrict__ bn_b,
               const float* __restrict__ bn_rm,
               const float* __restrict__ bn_rv,
               const float* __restrict__ W2,
               const float* __restrict__ b2,
               const float* __restrict__ ln_g,
               const float* __restrict__ ln_b,
               float* __restrict__ out,
               int N)
{
    __shared__ u16 h_lds[128][LDK];
    __shared__ u16 w_lds[128][LDK];

    const int tid = threadIdx.x;
    const int n0  = blockIdx.x * 128;
    const float epf = 1.0f + epsp[0];

    {
        const int row = tid >> 1;
        const int c0  = (tid & 1) * 64;
        int nrow = n0 + row; if (nrow >= N) nrow = N - 1;
        const float4* gx = reinterpret_cast<const float4*>(x    + (size_t)nrow * D + c0);
        const float4* ga = reinterpret_cast<const float4*>(aggr + (size_t)nrow * D + c0);
        const float4* gw = reinterpret_cast<const float4*>(W1   + (size_t)row  * D + c0);
        #pragma unroll
        for (int j = 0; j < 8; ++j) {
            float4 xv0 = gx[2*j], xv1 = gx[2*j+1];
            float4 av0 = ga[2*j], av1 = ga[2*j+1];
            float4 h0, h1;
            h0.x = epf*xv0.x + av0.x; h0.y = epf*xv0.y + av0.y;
            h0.z = epf*xv0.z + av0.z; h0.w = epf*xv0.w + av0.w;
            h1.x = epf*xv1.x + av1.x; h1.y = epf*xv1.y + av1.y;
            h1.z = epf*xv1.z + av1.z; h1.w = epf*xv1.w + av1.w;
            cvt_store8(&h_lds[row][c0 + 8*j], h0, h1);
            float4 w0 = gw[2*j], w1 = gw[2*j+1];
            cvt_store8(&w_lds[row][c0 + 8*j], w0, w1);
        }
    }
    __syncthreads();

    const int wave = tid >> 6, lane = tid & 63;
    const int lhi = lane >> 4, llo = lane & 15;
    const int r0 = wave * 32;

    f32x4 acc[2][8];
    #pragma unroll
    for (int m = 0; m < 2; ++m)
        #pragma unroll
        for (int n = 0; n < 8; ++n) acc[m][n] = (f32x4){0.f, 0.f, 0.f, 0.f};

    #pragma unroll
    for (int kk = 0; kk < 4; ++kk) {
        const int k0 = kk * 32 + lhi * 8;
        bf16x8 a0 = *reinterpret_cast<const bf16x8*>(&h_lds[r0 + llo][k0]);
        bf16x8 a1 = *reinterpret_cast<const bf16x8*>(&h_lds[r0 + 16 + llo][k0]);
        #pragma unroll
        for (int nf = 0; nf < 8; ++nf) {
            bf16x8 b = *reinterpret_cast<const bf16x8*>(&w_lds[nf*16 + llo][k0]);
            acc[0][nf] = __builtin_amdgcn_mfma_f32_16x16x32_bf16(a0, b, acc[0][nf], 0, 0, 0);
            acc[1][nf] = __builtin_amdgcn_mfma_f32_16x16x32_bf16(a1, b, acc[1][nf], 0, 0, 0);
        }
    }

    float sc[8], bi[8], b2v[8], lgv[8], lbv[8];
    #pragma unroll
    for (int nf = 0; nf < 8; ++nf) {
        const int c = nf*16 + llo;
        const float s = bn_g[c] * rsqrtf(bn_rv[c] + 1e-5f);
        sc[nf]  = s;
        bi[nf]  = (b1[c] - bn_rm[c]) * s + bn_b[c];
        b2v[nf] = b2[c];
        lgv[nf] = ln_g[c];
        lbv[nf] = ln_b[c];
    }

    __syncthreads();

    #pragma unroll
    for (int mf = 0; mf < 2; ++mf) {
        #pragma unroll
        for (int r = 0; r < 4; ++r) {
            const int row = r0 + mf*16 + lhi*4 + r;
            #pragma unroll
            for (int nf = 0; nf < 8; ++nf) {
                const int col = nf*16 + llo;
                const float v = fmaxf(acc[mf][nf][r] * sc[nf] + bi[nf], 0.0f);
                h_lds[row][col] = f2bf(v);
            }
        }
    }
    {
        const int row = tid >> 1;
        const int c0  = (tid & 1) * 64;
        const float4* gw = reinterpret_cast<const float4*>(W2 + (size_t)row * D + c0);
        #pragma unroll
        for (int j = 0; j < 8; ++j) {
            float4 w0 = gw[2*j], w1 = gw[2*j+1];
            cvt_store8(&w_lds[row][c0 + 8*j], w0, w1);
        }
    }
    __syncthreads();

    f32x4 acc2[2][8];
    #pragma unroll
    for (int m = 0; m < 2; ++m)
        #pragma unroll
        for (int n = 0; n < 8; ++n) acc2[m][n] = (f32x4){0.f, 0.f, 0.f, 0.f};

    #pragma unroll
    for (int kk = 0; kk < 4; ++kk) {
        const int k0 = kk * 32 + lhi * 8;
        bf16x8 a0 = *reinterpret_cast<const bf16x8*>(&h_lds[r0 + llo][k0]);
        bf16x8 a1 = *reinterpret_cast<const bf16x8*>(&h_lds[r0 + 16 + llo][k0]);
        #pragma unroll
        for (int nf = 0; nf < 8; ++nf) {
            bf16x8 b = *reinterpret_cast<const bf16x8*>(&w_lds[nf*16 + llo][k0]);
            acc2[0][nf] = __builtin_amdgcn_mfma_f32_16x16x32_bf16(a0, b, acc2[0][nf], 0, 0, 0);
            acc2[1][nf] = __builtin_amdgcn_mfma_f32_16x16x32_bf16(a1, b, acc2[1][nf], 0, 0, 0);
        }
    }

    #pragma unroll
    for (int mf = 0; mf < 2; ++mf) {
        #pragma unroll
        for (int r = 0; r < 4; ++r) {
            float hv[8];
            float ssum = 0.f;
            #pragma unroll
            for (int nf = 0; nf < 8; ++nf) {
                const float v = acc2[mf][nf][r] + b2v[nf];
                hv[nf] = v; ssum += v;
            }
            ssum += __shfl_xor(ssum, 1); ssum += __shfl_xor(ssum, 2);
            ssum += __shfl_xor(ssum, 4); ssum += __shfl_xor(ssum, 8);
            const float mu = ssum * (1.0f/128.0f);
            float qs = 0.f;
            #pragma unroll
            for (int nf = 0; nf < 8; ++nf) { const float dd = hv[nf] - mu; qs += dd*dd; }
            qs += __shfl_xor(qs, 1); qs += __shfl_xor(qs, 2);
            qs += __shfl_xor(qs, 4); qs += __shfl_xor(qs, 8);
            const float rstd = rsqrtf(qs * (1.0f/128.0f) + 1e-5f);

            const int nrow = n0 + r0 + mf*16 + lhi*4 + r;
            if (nrow < N) {
                const float* xr   = x   + (size_t)nrow * D;
                float*       orow = out + (size_t)nrow * D;
                #pragma unroll
                for (int nf = 0; nf < 8; ++nf) {
                    const int col = nf*16 + llo;
                    const float v = (hv[nf] - mu) * rstd * lgv[nf] + lbv[nf] + xr[col];
                    orow[col] = fmaxf(v, 0.0f);
                }
            }
        }
    }
}

extern "C" void kernel_launch(void* const* d_in, const int* in_sizes, int n_in,
                              void* d_out, int out_size, void* d_ws, size_t ws_size,
                              hipStream_t stream) {
    const float* x     = (const float*)d_in[0];
    const int*   ei    = (const int*)d_in[1];
    const float* ea    = (const float*)d_in[2];
    const float* epsp  = (const float*)d_in[3];
    const float* We    = (const float*)d_in[4];
    const float* be    = (const float*)d_in[5];
    const float* W1    = (const float*)d_in[6];
    const float* b1    = (const float*)d_in[7];
    const float* bn_g  = (const float*)d_in[8];
    const float* bn_b  = (const float*)d_in[9];
    const float* bn_rm = (const float*)d_in[10];
    const float* bn_rv = (const float*)d_in[11];
    const float* W2    = (const float*)d_in[12];
    const float* b2    = (const float*)d_in[13];
    const float* ln_g  = (const float*)d_in[14];
    const float* ln_b  = (const float*)d_in[15];
    float* out = (float*)d_out;

    const int N = in_sizes[0] / D;     // 50000
    const int E = in_sizes[2] / D;     // 800000

    const size_t aggr_bytes = (size_t)N * D * sizeof(float);        // 25.6 MB
    const size_t cnt_elems  = ((size_t)N + 1023) & ~(size_t)1023;
    const size_t cnt_bytes  = cnt_elems * sizeof(int);
    const size_t bsum_bytes = 1024;
    const size_t rec8_bytes = (size_t)E * sizeof(u64);              // 6.4 MB
    const size_t xbf_bytes  = (size_t)N * D * sizeof(u16);          // 12.8 MB
    const size_t base       = aggr_bytes + 2 * cnt_bytes + bsum_bytes;
    const size_t need_mid   = base + rec8_bytes + xbf_bytes;        // ~46 MB
    const int nsb = (int)(cnt_elems / 1024);
    const bool packable = (E < (1 << 20)) && (N < (1 << 17));

    char* wsb = (char*)d_ws;
    const int tblocks = (E + 255) / 256;
    const int eblocks = (E + 127) / 128;
    const int nblocks = (N + 127) / 128;
    const int ntiles  = (E + 127) / 128;
    const int pblocks = (ntiles < 512) ? ntiles : 512;   // 2 blocks/CU
    const int total8  = N * D / 8;
    const int xblocks = (total8 + 255) / 256;

    if (ws_size >= need_mid && nsb <= 256 && packable) {
        float* aggr    = (float*)(wsb);
        int*   counts  = (int*)(wsb + aggr_bytes);
        int*   offsets = (int*)(wsb + aggr_bytes + cnt_bytes);
        int*   bsum    = (int*)(wsb + aggr_bytes + 2*cnt_bytes);
        u64*   rec     = (u64*)(wsb + base);
        u16*   xbf     = (u16*)(wsb + base + rec8_bytes);

        (void)hipMemsetAsync(aggr, 0, aggr_bytes, stream);
        (void)hipMemsetAsync(counts, 0, cnt_bytes, stream);

        pre_kernel<<<xblocks + tblocks, 256, 0, stream>>>(x, xbf, total8, ei, counts, E, xblocks);
        scan_partial<<<nsb, 256, 0, stream>>>(counts, bsum);
        scan_bsum<<<1, 256, 0, stream>>>(bsum, nsb);
        scan_emit<<<nsb, 256, 0, stream>>>(counts, bsum, offsets);
        scatter_kernel<<<tblocks, 256, 0, stream>>>(ei, offsets, rec, E);

        gine_edge_pers<<<pblocks, 256, 0, stream>>>(xbf, ea, We, be, rec, aggr, E, ntiles);
        gine_node<<<nblocks, 256, 0, stream>>>(x, aggr, epsp, W1, b1, bn_g, bn_b,
                                               bn_rm, bn_rv, W2, b2, ln_g, ln_b, out, N);
    } else {
        float* aggr = (ws_size >= aggr_bytes) ? (float*)d_ws : out;
        (void)hipMemsetAsync(aggr, 0, aggr_bytes, stream);
        gine_edge<<<eblocks, 256, 0, stream>>>(x, ei, ea, We, be, aggr, E);
        gine_node<<<nblocks, 256, 0, stream>>>(x, aggr, epsp, W1, b1, bn_g, bn_b,
                                               bn_rm, bn_rv, W2, b2, ln_g, ln_b, out, N);
    }
}

// Round 15
// 341.114 us; speedup vs baseline: 1.0202x; 1.0202x over previous
//
#include <hip/hip_runtime.h>
#include <hip/hip_bf16.h>

#define D 128
#define LDK 136  // padded LDS row: 136 bf16 = 272B

typedef __bf16 bf16x8 __attribute__((ext_vector_type(8)));
typedef float  f32x4  __attribute__((ext_vector_type(4)));
typedef unsigned int u32x4 __attribute__((ext_vector_type(4)));
typedef unsigned short u16;

__device__ __forceinline__ u16 f2bf(float f) {
    unsigned int u = __builtin_bit_cast(unsigned int, f);
    u = u + 0x7FFFu + ((u >> 16) & 1u);
    return (u16)(u >> 16);
}
__device__ __forceinline__ float bf2f(u16 h) {
    unsigned int u = ((unsigned int)h) << 16;
    return __builtin_bit_cast(float, u);
}
__device__ __forceinline__ unsigned int pk2(float lo, float hi) {
    return (unsigned int)f2bf(lo) | ((unsigned int)f2bf(hi) << 16);
}
__device__ __forceinline__ void cvt_store8(u16* dst, float4 a, float4 b) {
    uint4 v;
    v.x = pk2(a.x, a.y); v.y = pk2(a.z, a.w);
    v.z = pk2(b.x, b.y); v.w = pk2(b.z, b.w);
    *reinterpret_cast<uint4*>(dst) = v;
}
__device__ __forceinline__ bf16x8 cvt8r(f32x4 a, f32x4 b) {
    u32x4 v;
    v.x = pk2(a.x, a.y); v.y = pk2(a.z, a.w);
    v.z = pk2(b.x, b.y); v.w = pk2(b.z, b.w);
    return __builtin_bit_cast(bf16x8, v);
}

// ======== x -> bf16 pre-conversion (sequential streaming, ~5us) ========
__global__ __launch_bounds__(256)
void xcvt_kernel(const float* __restrict__ x, u16* __restrict__ xbf, int total8) {
    int i = blockIdx.x * 256 + threadIdx.x;
    if (i < total8) {
        const f32x4* g = reinterpret_cast<const f32x4*>(x + (size_t)i * 8);
        f32x4 a = g[0], b = g[1];
        u32x4 v;
        v.x = pk2(a.x, a.y); v.y = pk2(a.z, a.w);
        v.z = pk2(b.x, b.y); v.w = pk2(b.z, b.w);
        *reinterpret_cast<u32x4*>(xbf + (size_t)i * 8) = v;
    }
}

// ======== counting sort of edges by dst ========
__global__ __launch_bounds__(256)
void hist_kernel(const int* __restrict__ ei, int* __restrict__ counts, int E) {
    int e = blockIdx.x * 256 + threadIdx.x;
    if (e < E) atomicAdd(&counts[ei[E + e]], 1);
}
__global__ __launch_bounds__(256)
void scan_partial(const int* __restrict__ counts, int* __restrict__ bsum) {
    const int b = blockIdx.x, t = threadIdx.x;
    const int4 v = reinterpret_cast<const int4*>(counts + (size_t)b * 1024)[t];
    int s = v.x + v.y + v.z + v.w;
    #pragma unroll
    for (int off = 1; off < 64; off <<= 1) s += __shfl_xor(s, off);
    __shared__ int ws[4];
    if ((t & 63) == 0) ws[t >> 6] = s;
    __syncthreads();
    if (t == 0) bsum[b] = ws[0] + ws[1] + ws[2] + ws[3];
}
__global__ __launch_bounds__(256)
void scan_bsum(int* __restrict__ bsum, int nb) {
    const int t = threadIdx.x;
    int s = (t < nb) ? bsum[t] : 0;
    int inc = s;
    const int lane = t & 63;
    #pragma unroll
    for (int off = 1; off < 64; off <<= 1) {
        int v = __shfl_up(inc, off);
        if (lane >= off) inc += v;
    }
    __shared__ int ws[4];
    if (lane == 63) ws[t >> 6] = inc;
    __syncthreads();
    int woff = 0;
    for (int i = 0; i < (t >> 6); ++i) woff += ws[i];
    if (t < nb) bsum[t] = woff + inc - s;
}
__global__ __launch_bounds__(256)
void scan_emit(const int* __restrict__ counts, const int* __restrict__ bsum,
               int* __restrict__ offsets) {
    const int b = blockIdx.x, t = threadIdx.x;
    const int4 v = reinterpret_cast<const int4*>(counts + (size_t)b * 1024)[t];
    const int s = v.x + v.y + v.z + v.w;
    int inc = s;
    const int lane = t & 63;
    #pragma unroll
    for (int off = 1; off < 64; off <<= 1) {
        int u = __shfl_up(inc, off);
        if (lane >= off) inc += u;
    }
    __shared__ int ws[4];
    if (lane == 63) ws[t >> 6] = inc;
    __syncthreads();
    int woff = bsum[b];
    for (int i = 0; i < (t >> 6); ++i) woff += ws[i];
    int e0 = woff + inc - s;
    int4 o;
    o.x = e0; o.y = e0 + v.x; o.z = o.y + v.y; o.w = o.z + v.z;
    reinterpret_cast<int4*>(offsets + (size_t)b * 1024)[t] = o;
}
__global__ __launch_bounds__(256)
void scatter_kernel(const int* __restrict__ ei, int* __restrict__ off,
                    int4* __restrict__ rec, int E) {
    int e = blockIdx.x * 256 + threadIdx.x;
    if (e < E) {
        int s = ei[e];
        int d = ei[E + e];
        int p = atomicAdd(&off[d], 1);
        rec[p] = make_int4(e, s, d, 0);
    }
}

// ======== persistent sorted edge kernel: We resident, bf16 x gather ========
__global__ __launch_bounds__(256, 2)
void gine_edge_pers(const u16* __restrict__ xbf,
                    const float* __restrict__ ea,
                    const float* __restrict__ We,
                    const float* __restrict__ be,
                    const int4* __restrict__ rec,
                    float* __restrict__ aggr,
                    int E, int ntiles)
{
    __shared__ u16 wbuf[128][LDK];   // We bf16, RESIDENT across tiles
    __shared__ u16 mbuf[128][LDK];   // x -> msg per tile
    __shared__ int eid_lds[128];
    __shared__ int src_lds[128];
    __shared__ int dst_lds[128];

    const int tid = threadIdx.x;
    const int wave = tid >> 6, lane = tid & 63;
    const int lhi = lane >> 4, llo = lane & 15;
    const int r0 = wave * 32;

    {   // stage We ONCE
        const int row = tid >> 1;
        const int c0  = (tid & 1) * 64;
        const float4* gw = reinterpret_cast<const float4*>(We + (size_t)row * D + c0);
        #pragma unroll
        for (int j = 0; j < 8; ++j) {
            float4 w0 = gw[2*j], w1 = gw[2*j+1];
            cvt_store8(&wbuf[row][c0 + 8*j], w0, w1);
        }
    }
    float bev[8];
    #pragma unroll
    for (int nf = 0; nf < 8; ++nf) bev[nf] = be[nf*16 + llo];
    __syncthreads();

    const int xrow = tid >> 1;
    const int xc0  = (tid & 1) * 64;

    for (int tile = blockIdx.x; tile < ntiles; tile += gridDim.x) {
        const int e0 = tile * 128;

        if (tid < 128) {   // stage sorted records (coalesced int4)
            const int p = e0 + tid;
            if (p < E) {
                int4 r4 = rec[p];
                eid_lds[tid] = r4.x; src_lds[tid] = r4.y; dst_lds[tid] = r4.z;
            } else {
                eid_lds[tid] = 0; src_lds[tid] = 0; dst_lds[tid] = -1;
            }
        }
        __syncthreads();   // B1: rec visible; prev tile's reduce done (mbuf free)

        f32x4 acc[2][8];
        #pragma unroll
        for (int m = 0; m < 2; ++m)
            #pragma unroll
            for (int n = 0; n < 8; ++n) acc[m][n] = (f32x4){0.f, 0.f, 0.f, 0.f};

        const f32x4* pa = reinterpret_cast<const f32x4*>(ea + (size_t)eid_lds[r0 + llo] * D);
        const f32x4* pb = reinterpret_cast<const f32x4*>(ea + (size_t)eid_lds[r0 + 16 + llo] * D);
        const u32x4* gx = reinterpret_cast<const u32x4*>(xbf + (size_t)src_lds[xrow] * D + xc0);

#define LOADG(G, KK) { const int f4_ = ((KK)*32 + lhi*8) >> 2;                 \
        G[0] = __builtin_nontemporal_load(pa + f4_);                           \
        G[1] = __builtin_nontemporal_load(pa + f4_ + 1);                       \
        G[2] = __builtin_nontemporal_load(pb + f4_);                           \
        G[3] = __builtin_nontemporal_load(pb + f4_ + 1); }
#define MFMAG(G, KK) { bf16x8 a0_ = cvt8r(G[0], G[1]);                         \
        bf16x8 a1_ = cvt8r(G[2], G[3]);                                        \
        const int k0_ = (KK)*32 + lhi*8;                                       \
        _Pragma("unroll")                                                      \
        for (int nf = 0; nf < 8; ++nf) {                                       \
            bf16x8 b_ = *reinterpret_cast<const bf16x8*>(&wbuf[nf*16 + llo][k0_]); \
            acc[0][nf] = __builtin_amdgcn_mfma_f32_16x16x32_bf16(a0_, b_, acc[0][nf], 0, 0, 0); \
            acc[1][nf] = __builtin_amdgcn_mfma_f32_16x16x32_bf16(a1_, b_, acc[1][nf], 0, 0, 0); \
        } }

        f32x4 gA[4], gB[4];
        u32x4 xa[8];
        LOADG(gA, 0); LOADG(gB, 1);
        #pragma unroll
        for (int j = 0; j < 8; ++j) xa[j] = gx[j];      // T14: x row (128B bf16) flies under MFMA
        MFMAG(gA, 0); LOADG(gA, 2);
        MFMAG(gB, 1); LOADG(gB, 3);
        MFMAG(gA, 2); MFMAG(gB, 3);
#undef LOADG
#undef MFMAG

        // store x to LDS (straight copies, wave-local rows: no barrier needed)
        #pragma unroll
        for (int j = 0; j < 8; ++j)
            *reinterpret_cast<u32x4*>(&mbuf[xrow][xc0 + 8*j]) = xa[j];

        // in-place epilogue (wave-local): mbuf[row][col] = relu(acc + x + be)
        #pragma unroll
        for (int mf = 0; mf < 2; ++mf) {
            #pragma unroll
            for (int r = 0; r < 4; ++r) {
                const int row = r0 + mf*16 + lhi*4 + r;
                const bool valid = (e0 + row) < E;
                #pragma unroll
                for (int nf = 0; nf < 8; ++nf) {
                    const int col = nf*16 + llo;
                    const float v = acc[mf][nf][r] + bf2f(mbuf[row][col]) + bev[nf];
                    mbuf[row][col] = valid ? f2bf(fmaxf(v, 0.0f)) : (u16)0;
                }
            }
        }
        __syncthreads();   // B2: all msg rows visible to reduce

        // segmented reduce, 2 halves (interior run -> exclusive store; boundary -> atomic)
        {
            const int c   = tid & 127;
            const int h   = tid >> 7;
            const int rlo = h * 64;
            float sum = 0.0f;
            int prev  = dst_lds[rlo];
            int start = rlo;
            #pragma unroll 4
            for (int r = rlo; r < rlo + 64; ++r) {
                const float v = bf2f(mbuf[r][c]);
                const int d = dst_lds[r];
                if (d != prev) {
                    if (prev >= 0) {
                        float* p = &aggr[(size_t)prev * D + c];
                        if (start == rlo) atomicAdd(p, sum);
                        else              *p = sum;
                    }
                    sum = 0.0f; prev = d; start = r;
                }
                sum += v;
            }
            if (prev >= 0) atomicAdd(&aggr[(size_t)prev * D + c], sum);
        }
        __syncthreads();   // B3: reduce done before next tile overwrites LDS
    }
}

// ======== last-resort unsorted edge kernel (ws too small) ========
__global__ __launch_bounds__(256, 4)
void gine_edge(const float* __restrict__ x,
               const int* __restrict__ ei,
               const float* __restrict__ ea,
               const float* __restrict__ We,
               const float* __restrict__ be,
               float* __restrict__ aggr,
               int E)
{
    __shared__ u16 w_lds[128][LDK];
    __shared__ int sd_lds[2][128];

    const int tid = threadIdx.x;
    const int e0  = blockIdx.x * 128;

    {
        const int row = tid >> 1;
        const int c0  = (tid & 1) * 64;
        const float4* gw = reinterpret_cast<const float4*>(We + (size_t)row * D + c0);
        #pragma unroll
        for (int j = 0; j < 8; ++j) {
            float4 w0 = gw[2*j], w1 = gw[2*j+1];
            cvt_store8(&w_lds[row][c0 + 8*j], w0, w1);
        }
        const int r = tid & 127, which = tid >> 7;
        int erow = e0 + r;
        sd_lds[which][r] = (erow < E) ? ei[(size_t)which * E + erow] : 0;
    }
    __syncthreads();

    const int wave = tid >> 6, lane = tid & 63;
    const int lhi = lane >> 4, llo = lane & 15;
    const int r0 = wave * 32;

    f32x4 acc[2][8];
    #pragma unroll
    for (int m = 0; m < 2; ++m)
        #pragma unroll
        for (int n = 0; n < 8; ++n) acc[m][n] = (f32x4){0.f, 0.f, 0.f, 0.f};

    int ra = e0 + r0 + llo;      if (ra >= E) ra = E - 1;
    int rb = e0 + r0 + 16 + llo; if (rb >= E) rb = E - 1;
    const f32x4* pa = reinterpret_cast<const f32x4*>(ea + (size_t)ra * D);
    const f32x4* pb = reinterpret_cast<const f32x4*>(ea + (size_t)rb * D);

    #pragma unroll
    for (int kk = 0; kk < 4; ++kk) {
        const int k0 = kk * 32 + lhi * 8;
        const int f4 = k0 >> 2;
        f32x4 u0 = __builtin_nontemporal_load(pa + f4);
        f32x4 u1 = __builtin_nontemporal_load(pa + f4 + 1);
        f32x4 v0 = __builtin_nontemporal_load(pb + f4);
        f32x4 v1 = __builtin_nontemporal_load(pb + f4 + 1);
        bf16x8 a0 = cvt8r(u0, u1);
        bf16x8 a1 = cvt8r(v0, v1);
        #pragma unroll
        for (int nf = 0; nf < 8; ++nf) {
            bf16x8 b = *reinterpret_cast<const bf16x8*>(&w_lds[nf*16 + llo][k0]);
            acc[0][nf] = __builtin_amdgcn_mfma_f32_16x16x32_bf16(a0, b, acc[0][nf], 0, 0, 0);
            acc[1][nf] = __builtin_amdgcn_mfma_f32_16x16x32_bf16(a1, b, acc[1][nf], 0, 0, 0);
        }
    }

    float bev[8];
    #pragma unroll
    for (int nf = 0; nf < 8; ++nf) bev[nf] = be[nf*16 + llo];

    #pragma unroll
    for (int mf = 0; mf < 2; ++mf) {
        #pragma unroll
        for (int r = 0; r < 4; ++r) {
            const int row = r0 + mf*16 + lhi*4 + r;
            if (e0 + row >= E) continue;
            const int s = sd_lds[0][row];
            const int d = sd_lds[1][row];
            const float* xr  = x    + (size_t)s * D;
            float*      arow = aggr + (size_t)d * D;
            #pragma unroll
            for (int nf = 0; nf < 8; ++nf) {
                const int col = nf*16 + llo;
                float v = acc[mf][nf][r] + xr[col] + bev[nf];
                atomicAdd(&arow[col], fmaxf(v, 0.0f));
            }
        }
    }
}

// ---------------- node kernel ----------------
__global__ __launch_bounds__(256, 2)
void gine_node(const float* __restrict__ x,
               const float* __restrict__ aggr,
               const float* __restrict__ epsp,
               const float* __restrict__ W1,
               const float* __restrict__ b1,
               const float* __restrict__ bn_g,
               const float* __restrict__ bn_b,
               const float* __restrict__ bn_rm,
               const float* __restrict__ bn_rv,
               const float* __restrict__ W2,
               const float* __restrict__ b2,
               const float* __restrict__ ln_g,
               const float* __restrict__ ln_b,
               float* __restrict__ out,
               int N)
{
    __shared__ u16 h_lds[128][LDK];
    __shared__ u16 w_lds[128][LDK];

    const int tid = threadIdx.x;
    const int n0  = blockIdx.x * 128;
    const float epf = 1.0f + epsp[0];

    {
        const int row = tid >> 1;
        const int c0  = (tid & 1) * 64;
        int nrow = n0 + row; if (nrow >= N) nrow = N - 1;
        const float4* gx = reinterpret_cast<const float4*>(x    + (size_t)nrow * D + c0);
        const float4* ga = reinterpret_cast<const float4*>(aggr + (size_t)nrow * D + c0);
        const float4* gw = reinterpret_cast<const float4*>(W1   + (size_t)row  * D + c0);
        #pragma unroll
        for (int j = 0; j < 8; ++j) {
            float4 xv0 = gx[2*j], xv1 = gx[2*j+1];
            float4 av0 = ga[2*j], av1 = ga[2*j+1];
            float4 h0, h1;
            h0.x = epf*xv0.x + av0.x; h0.y = epf*xv0.y + av0.y;
            h0.z = epf*xv0.z + av0.z; h0.w = epf*xv0.w + av0.w;
            h1.x = epf*xv1.x + av1.x; h1.y = epf*xv1.y + av1.y;
            h1.z = epf*xv1.z + av1.z; h1.w = epf*xv1.w + av1.w;
            cvt_store8(&h_lds[row][c0 + 8*j], h0, h1);
            float4 w0 = gw[2*j], w1 = gw[2*j+1];
            cvt_store8(&w_lds[row][c0 + 8*j], w0, w1);
        }
    }
    __syncthreads();

    const int wave = tid >> 6, lane = tid & 63;
    const int lhi = lane >> 4, llo = lane & 15;
    const int r0 = wave * 32;

    f32x4 acc[2][8];
    #pragma unroll
    for (int m = 0; m < 2; ++m)
        #pragma unroll
        for (int n = 0; n < 8; ++n) acc[m][n] = (f32x4){0.f, 0.f, 0.f, 0.f};

    #pragma unroll
    for (int kk = 0; kk < 4; ++kk) {
        const int k0 = kk * 32 + lhi * 8;
        bf16x8 a0 = *reinterpret_cast<const bf16x8*>(&h_lds[r0 + llo][k0]);
        bf16x8 a1 = *reinterpret_cast<const bf16x8*>(&h_lds[r0 + 16 + llo][k0]);
        #pragma unroll
        for (int nf = 0; nf < 8; ++nf) {
            bf16x8 b = *reinterpret_cast<const bf16x8*>(&w_lds[nf*16 + llo][k0]);
            acc[0][nf] = __builtin_amdgcn_mfma_f32_16x16x32_bf16(a0, b, acc[0][nf], 0, 0, 0);
            acc[1][nf] = __builtin_amdgcn_mfma_f32_16x16x32_bf16(a1, b, acc[1][nf], 0, 0, 0);
        }
    }

    float sc[8], bi[8], b2v[8], lgv[8], lbv[8];
    #pragma unroll
    for (int nf = 0; nf < 8; ++nf) {
        const int c = nf*16 + llo;
        const float s = bn_g[c] * rsqrtf(bn_rv[c] + 1e-5f);
        sc[nf]  = s;
        bi[nf]  = (b1[c] - bn_rm[c]) * s + bn_b[c];
        b2v[nf] = b2[c];
        lgv[nf] = ln_g[c];
        lbv[nf] = ln_b[c];
    }

    __syncthreads();

    #pragma unroll
    for (int mf = 0; mf < 2; ++mf) {
        #pragma unroll
        for (int r = 0; r < 4; ++r) {
            const int row = r0 + mf*16 + lhi*4 + r;
            #pragma unroll
            for (int nf = 0; nf < 8; ++nf) {
                const int col = nf*16 + llo;
                const float v = fmaxf(acc[mf][nf][r] * sc[nf] + bi[nf], 0.0f);
                h_lds[row][col] = f2bf(v);
            }
        }
    }
    {
        const int row = tid >> 1;
        const int c0  = (tid & 1) * 64;
        const float4* gw = reinterpret_cast<const float4*>(W2 + (size_t)row * D + c0);
        #pragma unroll
        for (int j = 0; j < 8; ++j) {
            float4 w0 = gw[2*j], w1 = gw[2*j+1];
            cvt_store8(&w_lds[row][c0 + 8*j], w0, w1);
        }
    }
    __syncthreads();

    f32x4 acc2[2][8];
    #pragma unroll
    for (int m = 0; m < 2; ++m)
        #pragma unroll
        for (int n = 0; n < 8; ++n) acc2[m][n] = (f32x4){0.f, 0.f, 0.f, 0.f};

    #pragma unroll
    for (int kk = 0; kk < 4; ++kk) {
        const int k0 = kk * 32 + lhi * 8;
        bf16x8 a0 = *reinterpret_cast<const bf16x8*>(&h_lds[r0 + llo][k0]);
        bf16x8 a1 = *reinterpret_cast<const bf16x8*>(&h_lds[r0 + 16 + llo][k0]);
        #pragma unroll
        for (int nf = 0; nf < 8; ++nf) {
            bf16x8 b = *reinterpret_cast<const bf16x8*>(&w_lds[nf*16 + llo][k0]);
            acc2[0][nf] = __builtin_amdgcn_mfma_f32_16x16x32_bf16(a0, b, acc2[0][nf], 0, 0, 0);
            acc2[1][nf] = __builtin_amdgcn_mfma_f32_16x16x32_bf16(a1, b, acc2[1][nf], 0, 0, 0);
        }
    }

    #pragma unroll
    for (int mf = 0; mf < 2; ++mf) {
        #pragma unroll
        for (int r = 0; r < 4; ++r) {
            float hv[8];
            float ssum = 0.f;
            #pragma unroll
            for (int nf = 0; nf < 8; ++nf) {
                const float v = acc2[mf][nf][r] + b2v[nf];
                hv[nf] = v; ssum += v;
            }
            ssum += __shfl_xor(ssum, 1); ssum += __shfl_xor(ssum, 2);
            ssum += __shfl_xor(ssum, 4); ssum += __shfl_xor(ssum, 8);
            const float mu = ssum * (1.0f/128.0f);
            float qs = 0.f;
            #pragma unroll
            for (int nf = 0; nf < 8; ++nf) { const float dd = hv[nf] - mu; qs += dd*dd; }
            qs += __shfl_xor(qs, 1); qs += __shfl_xor(qs, 2);
            qs += __shfl_xor(qs, 4); qs += __shfl_xor(qs, 8);
            const float rstd = rsqrtf(qs * (1.0f/128.0f) + 1e-5f);

            const int nrow = n0 + r0 + mf*16 + lhi*4 + r;
            if (nrow < N) {
                const float* xr   = x   + (size_t)nrow * D;
                float*       orow = out + (size_t)nrow * D;
                #pragma unroll
                for (int nf = 0; nf < 8; ++nf) {
                    const int col = nf*16 + llo;
                    const float v = (hv[nf] - mu) * rstd * lgv[nf] + lbv[nf] + xr[col];
                    orow[col] = fmaxf(v, 0.0f);
                }
            }
        }
    }
}

extern "C" void kernel_launch(void* const* d_in, const int* in_sizes, int n_in,
                              void* d_out, int out_size, void* d_ws, size_t ws_size,
                              hipStream_t stream) {
    const float* x     = (const float*)d_in[0];
    const int*   ei    = (const int*)d_in[1];
    const float* ea    = (const float*)d_in[2];
    const float* epsp  = (const float*)d_in[3];
    const float* We    = (const float*)d_in[4];
    const float* be    = (const float*)d_in[5];
    const float* W1    = (const float*)d_in[6];
    const float* b1    = (const float*)d_in[7];
    const float* bn_g  = (const float*)d_in[8];
    const float* bn_b  = (const float*)d_in[9];
    const float* bn_rm = (const float*)d_in[10];
    const float* bn_rv = (const float*)d_in[11];
    const float* W2    = (const float*)d_in[12];
    const float* b2    = (const float*)d_in[13];
    const float* ln_g  = (const float*)d_in[14];
    const float* ln_b  = (const float*)d_in[15];
    float* out = (float*)d_out;

    const int N = in_sizes[0] / D;     // 50000
    const int E = in_sizes[2] / D;     // 800000

    const size_t aggr_bytes = (size_t)N * D * sizeof(float);        // 25.6 MB
    const size_t cnt_elems  = ((size_t)N + 1023) & ~(size_t)1023;
    const size_t cnt_bytes  = cnt_elems * sizeof(int);
    const size_t bsum_bytes = 1024;
    const size_t rec4_bytes = (size_t)E * sizeof(int4);             // 12.8 MB
    const size_t xbf_bytes  = (size_t)N * D * sizeof(u16);          // 12.8 MB
    const size_t base       = aggr_bytes + 2 * cnt_bytes + bsum_bytes;
    const size_t need_mid   = base + rec4_bytes + xbf_bytes;        // ~52 MB
    const int nsb = (int)(cnt_elems / 1024);

    char* wsb = (char*)d_ws;
    const int tblocks = (E + 255) / 256;
    const int eblocks = (E + 127) / 128;
    const int nblocks = (N + 127) / 128;
    const int ntiles  = (E + 127) / 128;
    const int pblocks = (ntiles < 512) ? ntiles : 512;   // 2 blocks/CU
    const int total8  = N * D / 8;
    const int xblocks = (total8 + 255) / 256;

    if (ws_size >= need_mid && nsb <= 256) {
        float* aggr    = (float*)(wsb);
        int*   counts  = (int*)(wsb + aggr_bytes);
        int*   offsets = (int*)(wsb + aggr_bytes + cnt_bytes);
        int*   bsum    = (int*)(wsb + aggr_bytes + 2*cnt_bytes);
        int4*  rec     = (int4*)(wsb + base);
        u16*   xbf     = (u16*)(wsb + base + rec4_bytes);

        (void)hipMemsetAsync(aggr, 0, aggr_bytes, stream);
        (void)hipMemsetAsync(counts, 0, cnt_bytes, stream);

        xcvt_kernel<<<xblocks, 256, 0, stream>>>(x, xbf, total8);
        hist_kernel<<<tblocks, 256, 0, stream>>>(ei, counts, E);
        scan_partial<<<nsb, 256, 0, stream>>>(counts, bsum);
        scan_bsum<<<1, 256, 0, stream>>>(bsum, nsb);
        scan_emit<<<nsb, 256, 0, stream>>>(counts, bsum, offsets);
        scatter_kernel<<<tblocks, 256, 0, stream>>>(ei, offsets, rec, E);

        gine_edge_pers<<<pblocks, 256, 0, stream>>>(xbf, ea, We, be, rec, aggr, E, ntiles);
        gine_node<<<nblocks, 256, 0, stream>>>(x, aggr, epsp, W1, b1, bn_g, bn_b,
                                               bn_rm, bn_rv, W2, b2, ln_g, ln_b, out, N);
    } else {
        float* aggr = (ws_size >= aggr_bytes) ? (float*)d_ws : out;
        (void)hipMemsetAsync(aggr, 0, aggr_bytes, stream);
        gine_edge<<<eblocks, 256, 0, stream>>>(x, ei, ea, We, be, aggr, E);
        gine_node<<<nblocks, 256, 0, stream>>>(x, aggr, epsp, W1, b1, bn_g, bn_b,
                                               bn_rm, bn_rv, W2, b2, ln_g, ln_b, out, N);
    }
}